// Round 4
// baseline (407.177 us; speedup 1.0000x reference)
//
#include <hip/hip_runtime.h>
#include <math.h>

#define PGT 10000
#define CNT0 0x7F7F7F7Fu

// ws layout (bytes):
//   0   cntA (pg n==0 done, target +412)
//   4   cntB (pg all done,  target +1648)
//   8   cntC (gp done,      target +1760)
//   12  cntD (part writers, target +192)
//   [256, 480256)      gpmin   u32[3*4*10000] float-bits  (memset 0x7F -> 3.39e38)
//   [480384, 584064)   pg0min  u64[3240*4]  ((distbits<<32)|idx), plain stores (n==0)
//   [584064, 739584)   pgnmin  u32[3*3240*4] distbits, plain stores (n=1..3)
//   [739584, 741952)   part    double[296], pre-scaled, plain stores
// part slots: lap/move [0,104) bce [104,168) edge [168,220) norm [220,272)
//             pgred [272,284) gpred [284,296)
#define NSLOT 296

static __device__ __forceinline__ float waveReduceSum(float v) {
#pragma unroll
    for (int o = 32; o; o >>= 1) v += __shfl_down(v, o);
    return v;
}
static __device__ __forceinline__ double waveReduceSumD(double v) {
#pragma unroll
    for (int o = 32; o; o >>= 1) v += __shfl_down(v, o);
    return v;
}
static __device__ __forceinline__ float blockReduceF(float v, float* red) {
    v = waveReduceSum(v);
    __syncthreads();
    if ((threadIdx.x & 63) == 0) red[threadIdx.x >> 6] = v;
    __syncthreads();
    return red[0] + red[1] + red[2] + red[3];
}
static __device__ __forceinline__ double blockReduceD(double v, double* red) {
    v = waveReduceSumD(v);
    __syncthreads();
    if ((threadIdx.x & 63) == 0) red[threadIdx.x >> 6] = v;
    __syncthreads();
    return red[0] + red[1] + red[2] + red[3];
}
// producer signal: all block stores drained, then device-visible increment
static __device__ __forceinline__ void bump(unsigned* c) {
    __syncthreads();
    __threadfence();
    if (threadIdx.x == 0) atomicAdd(c, 1u);
}
// consumer wait: spin until counter == target, then acquire
static __device__ __forceinline__ void spin(unsigned* c, unsigned target) {
    if (threadIdx.x == 0) {
        while (atomicAdd(c, 0u) != target) __builtin_amdgcn_s_sleep(8);
    }
    __threadfence();
    __syncthreads();
}

// Block layout (producers first, batch-0 pg at the very front):
//  [0,412)      pg n==0 : 103 chunks(32 preds) x 4 q-quarters, argmin kept
//  [412,1648)   pg n>0  : 412 x 3 batches, min only
//  [1648,3408)  gp      : 11 groups(<=320 preds) x 4 n x 40 q-chunks -> atomicMin
//  [3408,3460)  laplace+move (52)
//  [3460,3524)  BCE (64)
//  [3524,3576)  edge+normal waiters (52, spin cntA)
//  [3576,3588)  pg reduce waiters (12, spin cntB)
//  [3588,3600)  gp reduce waiters (12, spin cntC)
__global__ __launch_bounds__(256) void p2m_kernel(
    const float* __restrict__ pc0, const float* __restrict__ pc1, const float* __restrict__ pc2,
    const float* __restrict__ pb0, const float* __restrict__ pb1, const float* __restrict__ pb2,
    const int* __restrict__ lp0, const int* __restrict__ lp1, const int* __restrict__ lp2,
    const int* __restrict__ e0, const int* __restrict__ e1, const int* __restrict__ e2,
    const float* __restrict__ gtp, const float* __restrict__ gtn,
    const float* __restrict__ gimg, const float* __restrict__ rec,
    unsigned* __restrict__ cnt, unsigned* __restrict__ gpmin,
    unsigned long long* __restrict__ pg0min, unsigned* __restrict__ pgnmin,
    double* __restrict__ part, float* __restrict__ out)
{
    __shared__ float s_p[160 * 8];
    __shared__ float s_red[4];
    __shared__ double s_redd[4];
    __shared__ int s_flag;
    const int b = blockIdx.x;
    const int tid = threadIdx.x;
    bool wrote_part = false;
    int part_e = -1, part_n = -1; float esum = 0.f, nsum = 0.f;  // for edge path

    if (b < 1648) {
        // ================= pg =================
        int n, v;
        if (b < 412) { n = 0; v = b; }
        else { int u = b - 412; n = u % 3 + 1; v = u / 3; }
        int h = v & 3, cc = v >> 2;
        int level, Pl, loff; const float* P;
        if (cc < 5)       { level = 0; Pl = 156;  loff = 0;   P = pc0; }
        else if (cc < 25) { level = 1; Pl = 618;  loff = 156; P = pc1; cc -= 5; }
        else              { level = 2; Pl = 2466; loff = 774; P = pc2; cc -= 25; }
        const int wave = tid >> 6, lane = tid & 63;
        const int pbase = cc * 32 + wave * 8;
        const float* pn = P + (size_t)n * Pl * 3;
        float px[8], py[8], pz[8];
#pragma unroll
        for (int j = 0; j < 8; j++) {
            int pi = pbase + j; int ps = (pi < Pl) ? pi : 0;
            px[j] = pn[ps * 3 + 0]; py[j] = pn[ps * 3 + 1]; pz[j] = pn[ps * 3 + 2];
        }
        const float* g3 = gtp + (size_t)n * PGT * 3;
        const int qbeg = h * 2500, qend = qbeg + 2500;   // 2500 = 19*128 + 68
        float bd[8];
#pragma unroll
        for (int j = 0; j < 8; j++) bd[j] = 3e38f;
        if (n == 0) {
            int bi[8];
#pragma unroll
            for (int j = 0; j < 8; j++) bi[j] = 0;
            int q0 = qbeg;
            for (; q0 + 128 <= qend; q0 += 128) {
                const float* ga = g3 + (q0 + lane) * 3;
                float2 X = {ga[0], ga[192]};
                float2 Y = {ga[1], ga[193]};
                float2 Z = {ga[2], ga[194]};
                float2 S;
                S.x = fmaf(X.x, X.x, fmaf(Y.x, Y.x, Z.x * Z.x));
                S.y = fmaf(X.y, X.y, fmaf(Y.y, Y.y, Z.y * Z.y));
                int qa = q0 + lane, qb = qa + 64;
#pragma unroll
                for (int j = 0; j < 8; j++) {
                    float tx = fmaf(px[j], X.x, fmaf(py[j], Y.x, pz[j] * Z.x));
                    float ty = fmaf(px[j], X.y, fmaf(py[j], Y.y, pz[j] * Z.y));
                    float dx = fmaf(-2.f, tx, S.x);   // |q|^2 - 2 p.q  (p^2 added later)
                    float dy = fmaf(-2.f, ty, S.y);
                    if (dx < bd[j]) { bd[j] = dx; bi[j] = qa; }
                    if (dy < bd[j]) { bd[j] = dy; bi[j] = qb; }
                }
            }
            for (; q0 < qend; q0 += 64) {
                int qt = q0 + lane;
                if (qt < qend) {
                    const float* ga = g3 + qt * 3;
                    float x = ga[0], y = ga[1], z = ga[2];
                    float s = fmaf(x, x, fmaf(y, y, z * z));
#pragma unroll
                    for (int j = 0; j < 8; j++) {
                        float d = fmaf(-2.f, fmaf(px[j], x, fmaf(py[j], y, pz[j] * z)), s);
                        if (d < bd[j]) { bd[j] = d; bi[j] = qt; }
                    }
                }
            }
#pragma unroll
            for (int j = 0; j < 8; j++) {
#pragma unroll
                for (int o = 1; o < 64; o <<= 1) {
                    float od = __shfl_xor(bd[j], o);
                    int   oi = __shfl_xor(bi[j], o);
                    if (od < bd[j] || (od == bd[j] && oi < bi[j])) { bd[j] = od; bi[j] = oi; }
                }
            }
            if (lane == 0) {
#pragma unroll
                for (int j = 0; j < 8; j++) {
                    int pi = pbase + j;
                    if (pi < Pl) {
                        float p2 = fmaf(px[j], px[j], fmaf(py[j], py[j], pz[j] * pz[j]));
                        float dv = fmaxf(bd[j] + p2, 0.f);
                        pg0min[(size_t)(loff + pi) * 4 + h] =
                            ((unsigned long long)__float_as_uint(dv) << 32) | (unsigned)bi[j];
                    }
                }
            }
        } else {
            int q0 = qbeg;
            for (; q0 + 128 <= qend; q0 += 128) {
                const float* ga = g3 + (q0 + lane) * 3;
                float2 X = {ga[0], ga[192]};
                float2 Y = {ga[1], ga[193]};
                float2 Z = {ga[2], ga[194]};
                float2 S;
                S.x = fmaf(X.x, X.x, fmaf(Y.x, Y.x, Z.x * Z.x));
                S.y = fmaf(X.y, X.y, fmaf(Y.y, Y.y, Z.y * Z.y));
#pragma unroll
                for (int j = 0; j < 8; j++) {
                    float tx = fmaf(px[j], X.x, fmaf(py[j], Y.x, pz[j] * Z.x));
                    float ty = fmaf(px[j], X.y, fmaf(py[j], Y.y, pz[j] * Z.y));
                    bd[j] = fminf(bd[j], fminf(fmaf(-2.f, tx, S.x), fmaf(-2.f, ty, S.y)));
                }
            }
            for (; q0 < qend; q0 += 64) {
                int qt = q0 + lane;
                if (qt < qend) {
                    const float* ga = g3 + qt * 3;
                    float x = ga[0], y = ga[1], z = ga[2];
                    float s = fmaf(x, x, fmaf(y, y, z * z));
#pragma unroll
                    for (int j = 0; j < 8; j++)
                        bd[j] = fminf(bd[j], fmaf(-2.f, fmaf(px[j], x, fmaf(py[j], y, pz[j] * z)), s));
                }
            }
#pragma unroll
            for (int j = 0; j < 8; j++) {
#pragma unroll
                for (int o = 1; o < 64; o <<= 1) bd[j] = fminf(bd[j], __shfl_xor(bd[j], o));
            }
            if (lane == 0) {
#pragma unroll
                for (int j = 0; j < 8; j++) {
                    int pi = pbase + j;
                    if (pi < Pl) {
                        float p2 = fmaf(px[j], px[j], fmaf(py[j], py[j], pz[j] * pz[j]));
                        pgnmin[(size_t)((n - 1) * 3240 + loff + pi) * 4 + h] =
                            __float_as_uint(fmaxf(bd[j] + p2, 0.f));
                    }
                }
            }
        }
        if (n == 0) bump(&cnt[0]);
        bump(&cnt[1]);
        return;
    }
    else if (b < 3408) {
        // ================= gp =================
        int t = b - 1648;
        int g = t / 160, tr = t % 160;
        int level, Pl, pstart; const float* P;
        if (g == 0)     { level = 0; Pl = 156;  P = pc0; pstart = 0; }
        else if (g < 3) { level = 1; Pl = 618;  P = pc1; pstart = (g - 1) * 320; }
        else            { level = 2; Pl = 2466; P = pc2; pstart = (g - 3) * 320; }
        int n = tr / 40, qc = tr % 40;
        int tp = Pl - pstart; if (tp > 320) tp = 320;      // all tp are even
        const float* pn = P + ((size_t)n * Pl + pstart) * 3;
        for (int i = tid; i < tp; i += 256) {              // pair-interleaved SoA
            float x = pn[i * 3 + 0], y = pn[i * 3 + 1], z = pn[i * 3 + 2];
            float* dst = &s_p[(i >> 1) * 8 + (i & 1)];
            dst[0] = x; dst[2] = y; dst[4] = z;
            dst[6] = fmaf(x, x, fmaf(y, y, z * z));
        }
        __syncthreads();
        int q = qc * 256 + tid; bool vq = (q < PGT);
        const float* g3 = gtp + (size_t)n * PGT * 3;
        float qx = 0.f, qy = 0.f, qz = 0.f;
        if (vq) { qx = g3[q * 3 + 0]; qy = g3[q * 3 + 1]; qz = g3[q * 3 + 2]; }
        float q2 = fmaf(qx, qx, fmaf(qy, qy, qz * qz));
        float bd = 3e38f;
        const int npairs = tp >> 1;
        int pp = 0;
        for (; pp + 4 <= npairs; pp += 4) {
#pragma unroll
            for (int u = 0; u < 4; u++) {
                const float2* sp = (const float2*)&s_p[(pp + u) * 8];
                float2 X = sp[0], Y = sp[1], Z = sp[2], S = sp[3];
                float tx = fmaf(X.x, qx, fmaf(Y.x, qy, Z.x * qz));
                float ty = fmaf(X.y, qx, fmaf(Y.y, qy, Z.y * qz));
                bd = fminf(bd, fminf(fmaf(-2.f, tx, S.x), fmaf(-2.f, ty, S.y)));
            }
        }
        for (; pp < npairs; pp++) {
            const float2* sp = (const float2*)&s_p[pp * 8];
            float2 X = sp[0], Y = sp[1], Z = sp[2], S = sp[3];
            float tx = fmaf(X.x, qx, fmaf(Y.x, qy, Z.x * qz));
            float ty = fmaf(X.y, qx, fmaf(Y.y, qy, Z.y * qz));
            bd = fminf(bd, fminf(fmaf(-2.f, tx, S.x), fmaf(-2.f, ty, S.y)));
        }
        if (vq) atomicMin(&gpmin[(level * 4 + n) * PGT + q], __float_as_uint(fmaxf(bd + q2, 0.f)));
        bump(&cnt[2]);
        return;
    }
    else if (b < 3460) {
        // ================= laplace + move =================
        int t = b - 3408;
        int level, Pl, bstart; const float* P; const float* B; const int* L;
        if (t < 3)       { level = 0; Pl = 156;  P = pc0; B = pb0; L = lp0; bstart = 0; }
        else if (t < 13) { level = 1; Pl = 618;  P = pc1; B = pb1; L = lp1; bstart = 3; }
        else             { level = 2; Pl = 2466; P = pc2; B = pb2; L = lp2; bstart = 13; }
        int item = (t - bstart) * 256 + tid;
        float lap_s = 0.f, mov_s = 0.f;
        if (item < 4 * Pl) {
            int n = item / Pl, p = item % Pl;
            const int* lr = L + p * 10;
            float cntv = (float)lr[9];
            const float* Bn = B + (size_t)n * Pl * 3;
            const float* Pn = P + (size_t)n * Pl * 3;
            float sbx = 0, sby = 0, sbz = 0, spx = 0, spy = 0, spz = 0;
#pragma unroll
            for (int k = 0; k < 8; k++) {
                int id = lr[k];
                if (id >= 0) {
                    sbx += Bn[id * 3 + 0]; sby += Bn[id * 3 + 1]; sbz += Bn[id * 3 + 2];
                    spx += Pn[id * 3 + 0]; spy += Pn[id * 3 + 1]; spz += Pn[id * 3 + 2];
                }
            }
            float bx = Bn[p * 3], by = Bn[p * 3 + 1], bz = Bn[p * 3 + 2];
            float vx = Pn[p * 3], vy = Pn[p * 3 + 1], vz = Pn[p * 3 + 2];
            float dx = (bx - sbx / cntv) - (vx - spx / cntv);
            float dy = (by - sby / cntv) - (vy - spy / cntv);
            float dz = (bz - sbz / cntv) - (vz - spz / cntv);
            lap_s = dx * dx + dy * dy + dz * dz;
            float mx = bx - vx, my = by - vy, mz = bz - vz;
            mov_s = mx * mx + my * my + mz * mz;
        }
        float lsum = blockReduceF(lap_s, s_red);
        float msum = blockReduceF(mov_s, s_red);
        if (tid == 0) {
            const double lc[3] = {0.2, 1.0, 1.0};
            double inv = 1.0 / (4.0 * (double)Pl);
            part[2 * t]     = (double)lsum * (0.5 * lc[level] * inv);
            part[2 * t + 1] = (level > 0) ? (double)msum * (0.1 * lc[level] * inv) : 0.0;
        }
        wrote_part = true;
    }
    else if (b < 3524) {
        // ================= BCE =================
        int t = b - 3460;
        const float4* g4 = (const float4*)gimg;
        const float4* r4 = (const float4*)rec;
        const int N4 = 602112 / 4;
        float s = 0.f;
        for (int i = t * 256 + tid; i < N4; i += 64 * 256) {
            float4 gv = g4[i], rv = r4[i];
            s -= gv.x * __logf(rv.x) + (1.f - gv.x) * __logf(1.f - rv.x);
            s -= gv.y * __logf(rv.y) + (1.f - gv.y) * __logf(1.f - rv.y);
            s -= gv.z * __logf(rv.z) + (1.f - gv.z) * __logf(1.f - rv.z);
            s -= gv.w * __logf(rv.w) + (1.f - gv.w) * __logf(1.f - rv.w);
        }
        float sum = blockReduceF(s, s_red);
        if (tid == 0) part[104 + t] = (double)sum / 602112.0;
        wrote_part = true;
    }
    else if (b < 3576) {
        // ================= edge + normal (waits on batch-0 pg) =================
        spin(&cnt[0], CNT0 + 412u);
        int brel = b - 3524;
        float es = 0.f, ns = 0.f;
        const float escl[3] = {0.1f / 1848.f, 0.1f / 7392.f, 0.1f / 29568.f};
        const float nscl[3] = {0.00016f / 1848.f, 0.00016f / 7392.f, 0.00016f / 29568.f};
        for (int item = brel * 256 + tid; item < 38808; item += 52 * 256) {
            int level, n, e, Pl, loff; const float* P; const int* E;
            if (item < 1848)      { level = 0; Pl = 156;  loff = 0;   P = pc0; E = e0; n = item / 462;  e = item % 462; }
            else if (item < 9240) { level = 1; Pl = 618;  loff = 156; P = pc1; E = e1; int r = item - 1848; n = r / 1848; e = r % 1848; }
            else                  { level = 2; Pl = 2466; loff = 774; P = pc2; E = e2; int r = item - 9240; n = r / 7392; e = r % 7392; }
            int a = E[e * 2 + 0], b2 = E[e * 2 + 1];
            const float* Pn = P + (size_t)n * Pl * 3;
            float ax = Pn[a * 3], ay = Pn[a * 3 + 1], az = Pn[a * 3 + 2];
            float bx = Pn[b2 * 3], by = Pn[b2 * 3 + 1], bz = Pn[b2 * 3 + 2];
            float ex = ax - bx, ey = ay - by, ez = az - bz;
            float el2 = ex * ex + ey * ey + ez * ez;
            es += el2 * escl[level];
            float einv = 1.f / fmaxf(sqrtf(el2), 1e-12f);
            const unsigned long long* kp = &pg0min[(size_t)(loff + a) * 4];
            unsigned long long k0 = kp[0] < kp[1] ? kp[0] : kp[1];
            unsigned long long k1 = kp[2] < kp[3] ? kp[2] : kp[3];
            unsigned long long k = k0 < k1 ? k0 : k1;
            int ig = (int)(k & 0xFFFFFFFFull);
            const float* Nv = gtn + ((size_t)n * PGT + ig) * 3;
            float nx = Nv[0], ny = Nv[1], nz = Nv[2];
            float ninv = 1.f / fmaxf(sqrtf(nx * nx + ny * ny + nz * nz), 1e-12f);
            ns += fabsf((ex * nx + ey * ny + ez * nz) * einv * ninv) * nscl[level];
        }
        float esb = blockReduceF(es, s_red);
        float nsb = blockReduceF(ns, s_red);
        if (tid == 0) { part[168 + brel] = (double)esb; part[220 + brel] = (double)nsb; }
        wrote_part = true;
    }
    else if (b < 3588) {
        // ================= pg reduce (waits on all pg) =================
        spin(&cnt[1], CNT0 + 1648u);
        int i = b - 3576, level = i / 4, n = i % 4;
        int Pl = (level == 0) ? 156 : (level == 1) ? 618 : 2466;
        int loff = (level == 0) ? 0 : (level == 1) ? 156 : 774;
        double s = 0.0;
        if (n == 0) {
            const unsigned long long* base = &pg0min[(size_t)loff * 4];
            for (int p = tid; p < Pl; p += 256) {
                const unsigned long long* kp = &base[(size_t)p * 4];
                unsigned long long k0 = kp[0] < kp[1] ? kp[0] : kp[1];
                unsigned long long k1 = kp[2] < kp[3] ? kp[2] : kp[3];
                unsigned long long k = k0 < k1 ? k0 : k1;
                s += (double)__uint_as_float((unsigned)(k >> 32));
            }
        } else {
            const uint4* base = (const uint4*)&pgnmin[(size_t)((n - 1) * 3240 + loff) * 4];
            for (int p = tid; p < Pl; p += 256) {
                uint4 v = base[p];
                unsigned m = min(min(v.x, v.y), min(v.z, v.w));
                s += (double)__uint_as_float(m);
            }
        }
        s = blockReduceD(s, s_redd);
        if (tid == 0) part[272 + i] = s / (4.0 * (double)Pl);
        wrote_part = true;
    }
    else {
        // ================= gp reduce (waits on gp) =================
        spin(&cnt[2], CNT0 + 1760u);
        int i = b - 3588, level = i / 4, n = i % 4;
        const unsigned* gm = gpmin + (size_t)(level * 4 + n) * PGT;
        double s = 0.0;
        for (int q = tid; q < PGT; q += 256) s += (double)__uint_as_float(gm[q]);
        s = blockReduceD(s, s_redd);
        if (tid == 0) part[284 + i] = s * (0.55 / (4.0 * (double)PGT));
        wrote_part = true;
    }

    // ---- part writers: signal and last-one finalizes ----
    if (wrote_part) {
        __syncthreads();
        __threadfence();
        if (tid == 0) {
            unsigned old = atomicAdd(&cnt[3], 1u);
            s_flag = (old == CNT0 + 191u) ? 1 : 0;
            __threadfence();
        }
        __syncthreads();
        if (s_flag) {
            double s = 0.0;
            for (int i = tid; i < NSLOT; i += 256) s += part[i];
            s = blockReduceD(s, s_redd);
            if (tid == 0) out[0] = (float)s;
        }
    }
}

extern "C" void kernel_launch(void* const* d_in, const int* in_sizes, int n_in,
                              void* d_out, int out_size, void* d_ws, size_t ws_size,
                              hipStream_t stream) {
    const float *pc[3], *pb[3]; const int *ed[3], *lp[3];
    bool dict = (n_in >= 2 && in_sizes[1] == in_sizes[0]);   // dict vs signature order
    if (dict) {
        for (int i = 0; i < 3; i++) {
            pc[i] = (const float*)d_in[4 * i + 0];
            pb[i] = (const float*)d_in[4 * i + 1];
            ed[i] = (const int*)  d_in[4 * i + 2];
            lp[i] = (const int*)  d_in[4 * i + 3];
        }
    } else {
        for (int i = 0; i < 3; i++) {
            pc[i] = (const float*)d_in[i];
            pb[i] = (const float*)d_in[3 + i];
            ed[i] = (const int*)  d_in[6 + i];
            lp[i] = (const int*)  d_in[9 + i];
        }
    }
    const float* gtp  = (const float*)d_in[12];
    const float* gtn  = (const float*)d_in[13];
    const float* gimg = (const float*)d_in[14];
    const float* rec  = (const float*)d_in[15];

    unsigned*           cnt    = (unsigned*)d_ws;
    unsigned*           gpmin  = (unsigned*)((char*)d_ws + 256);
    unsigned long long* pg0min = (unsigned long long*)((char*)d_ws + 480384);
    unsigned*           pgnmin = (unsigned*)((char*)d_ws + 584064);
    double*             part   = (double*)((char*)d_ws + 739584);

    // one memset: counters -> 0x7F7F7F7F, gpmin -> 3.39e38f bits
    hipMemsetAsync(d_ws, 0x7F, 480256, stream);

    p2m_kernel<<<3600, 256, 0, stream>>>(pc[0], pc[1], pc[2], pb[0], pb[1], pb[2],
                                         lp[0], lp[1], lp[2], ed[0], ed[1], ed[2],
                                         gtp, gtn, gimg, rec,
                                         cnt, gpmin, pg0min, pgnmin, part, (float*)d_out);
}

// Round 5
// 159.786 us; speedup vs baseline: 2.5483x; 2.5483x over previous
//
#include <hip/hip_runtime.h>
#include <math.h>

#define PGT 10000
#define CNT0 0x7F7F7F7Fu

// ws layout (bytes):
//   0                  done counter (K2 only; memset 0x7F -> CNT0)
//   [256, 480256)      gpmin   u32[3*4*10000] float-bits  (memset 0x7F -> 3.39e38)
//   [480384, 584064)   pg0min  u64[3240*4]  ((distbits<<32)|idx), plain stores (n==0)
//   [584064, 739584)   pgnmin  u32[3*3240*4] distbits, plain stores (n=1..3)
//   [739584, +3984)    part    double[498], pre-scaled, plain stores
// part slots: lap/move [0,104) bce [104,168) edge [168,321) norm [321,474)
//             pgred [474,486) gpred [486,498)
#define NSLOT 498

static __device__ __forceinline__ float waveReduceSum(float v) {
#pragma unroll
    for (int o = 32; o; o >>= 1) v += __shfl_down(v, o);
    return v;
}
static __device__ __forceinline__ double waveReduceSumD(double v) {
#pragma unroll
    for (int o = 32; o; o >>= 1) v += __shfl_down(v, o);
    return v;
}
static __device__ __forceinline__ float blockReduceF(float v, float* red) {
    v = waveReduceSum(v);
    __syncthreads();
    if ((threadIdx.x & 63) == 0) red[threadIdx.x >> 6] = v;
    __syncthreads();
    return red[0] + red[1] + red[2] + red[3];
}
static __device__ __forceinline__ double blockReduceD(double v, double* red) {
    v = waveReduceSumD(v);
    __syncthreads();
    if ((threadIdx.x & 63) == 0) red[threadIdx.x >> 6] = v;
    __syncthreads();
    return red[0] + red[1] + red[2] + red[3];
}

// ---------------- K1 ----------------
//  [0,1648)     pg : 103 chunks(32 preds) x 4 q-quarters x 4 n; argmin kept for n==0
//  [1648,3408)  gp : 11 groups(<=320 preds) x 4 n x 40 q-chunks -> atomicMin
//  [3408,3460)  laplace+move (52)
//  [3460,3524)  BCE (64)
__global__ __launch_bounds__(256) void k1_kernel(
    const float* __restrict__ pc0, const float* __restrict__ pc1, const float* __restrict__ pc2,
    const float* __restrict__ pb0, const float* __restrict__ pb1, const float* __restrict__ pb2,
    const int* __restrict__ lp0, const int* __restrict__ lp1, const int* __restrict__ lp2,
    const float* __restrict__ gtp, const float* __restrict__ gimg, const float* __restrict__ rec,
    unsigned* __restrict__ gpmin, unsigned long long* __restrict__ pg0min,
    unsigned* __restrict__ pgnmin, double* __restrict__ part)
{
    __shared__ float4 s_tile[320];
    __shared__ float s_red[4];
    const int b = blockIdx.x;
    const int tid = threadIdx.x;

    if (b < 1648) {
        // ================= pg =================
        int n = b & 3, v = b >> 2;            // interleave n for tail balance
        int h = v & 3, cc = v >> 2;
        int level, Pl, loff; const float* P;
        if (cc < 5)       { level = 0; Pl = 156;  loff = 0;   P = pc0; }
        else if (cc < 25) { level = 1; Pl = 618;  loff = 156; P = pc1; cc -= 5; }
        else              { level = 2; Pl = 2466; loff = 774; P = pc2; cc -= 25; }
        const int wave = tid >> 6, lane = tid & 63;
        const int pbase = cc * 32 + wave * 8;
        const float* pn = P + (size_t)n * Pl * 3;
        float px[8], py[8], pz[8];
#pragma unroll
        for (int j = 0; j < 8; j++) {
            int pi = pbase + j; int ps = (pi < Pl) ? pi : 0;
            px[j] = pn[ps * 3 + 0]; py[j] = pn[ps * 3 + 1]; pz[j] = pn[ps * 3 + 2];
        }
        const float* g3 = gtp + (size_t)n * PGT * 3;
        const int qbeg = h * 2500, qend = qbeg + 2500;   // 2500 = 19*128 + 68
        float bd[8];
#pragma unroll
        for (int j = 0; j < 8; j++) bd[j] = 3e38f;
        if (n == 0) {
            int bi[8];
#pragma unroll
            for (int j = 0; j < 8; j++) bi[j] = 0;
            int q0 = qbeg;
            for (; q0 + 128 <= qend; q0 += 128) {
                const float* ga = g3 + (q0 + lane) * 3;
                float2 X = {ga[0], ga[192]};
                float2 Y = {ga[1], ga[193]};
                float2 Z = {ga[2], ga[194]};
                float2 S;
                S.x = fmaf(X.x, X.x, fmaf(Y.x, Y.x, Z.x * Z.x));
                S.y = fmaf(X.y, X.y, fmaf(Y.y, Y.y, Z.y * Z.y));
                int qa = q0 + lane, qb = qa + 64;
#pragma unroll
                for (int j = 0; j < 8; j++) {
                    float tx = fmaf(px[j], X.x, fmaf(py[j], Y.x, pz[j] * Z.x));
                    float ty = fmaf(px[j], X.y, fmaf(py[j], Y.y, pz[j] * Z.y));
                    float dx = fmaf(-2.f, tx, S.x);   // |q|^2 - 2 p.q  (p^2 added later)
                    float dy = fmaf(-2.f, ty, S.y);
                    if (dx < bd[j]) { bd[j] = dx; bi[j] = qa; }
                    if (dy < bd[j]) { bd[j] = dy; bi[j] = qb; }
                }
            }
            for (; q0 < qend; q0 += 64) {
                int qt = q0 + lane;
                if (qt < qend) {
                    const float* ga = g3 + qt * 3;
                    float x = ga[0], y = ga[1], z = ga[2];
                    float s = fmaf(x, x, fmaf(y, y, z * z));
#pragma unroll
                    for (int j = 0; j < 8; j++) {
                        float d = fmaf(-2.f, fmaf(px[j], x, fmaf(py[j], y, pz[j] * z)), s);
                        if (d < bd[j]) { bd[j] = d; bi[j] = qt; }
                    }
                }
            }
#pragma unroll
            for (int j = 0; j < 8; j++) {
#pragma unroll
                for (int o = 1; o < 64; o <<= 1) {
                    float od = __shfl_xor(bd[j], o);
                    int   oi = __shfl_xor(bi[j], o);
                    if (od < bd[j] || (od == bd[j] && oi < bi[j])) { bd[j] = od; bi[j] = oi; }
                }
            }
            if (lane == 0) {
#pragma unroll
                for (int j = 0; j < 8; j++) {
                    int pi = pbase + j;
                    if (pi < Pl) {
                        float p2 = fmaf(px[j], px[j], fmaf(py[j], py[j], pz[j] * pz[j]));
                        float dv = fmaxf(bd[j] + p2, 0.f);
                        pg0min[(size_t)(loff + pi) * 4 + h] =
                            ((unsigned long long)__float_as_uint(dv) << 32) | (unsigned)bi[j];
                    }
                }
            }
        } else {
            int q0 = qbeg;
            for (; q0 + 128 <= qend; q0 += 128) {
                const float* ga = g3 + (q0 + lane) * 3;
                float2 X = {ga[0], ga[192]};
                float2 Y = {ga[1], ga[193]};
                float2 Z = {ga[2], ga[194]};
                float2 S;
                S.x = fmaf(X.x, X.x, fmaf(Y.x, Y.x, Z.x * Z.x));
                S.y = fmaf(X.y, X.y, fmaf(Y.y, Y.y, Z.y * Z.y));
#pragma unroll
                for (int j = 0; j < 8; j++) {
                    float tx = fmaf(px[j], X.x, fmaf(py[j], Y.x, pz[j] * Z.x));
                    float ty = fmaf(px[j], X.y, fmaf(py[j], Y.y, pz[j] * Z.y));
                    bd[j] = fminf(bd[j], fminf(fmaf(-2.f, tx, S.x), fmaf(-2.f, ty, S.y)));
                }
            }
            for (; q0 < qend; q0 += 64) {
                int qt = q0 + lane;
                if (qt < qend) {
                    const float* ga = g3 + qt * 3;
                    float x = ga[0], y = ga[1], z = ga[2];
                    float s = fmaf(x, x, fmaf(y, y, z * z));
#pragma unroll
                    for (int j = 0; j < 8; j++)
                        bd[j] = fminf(bd[j], fmaf(-2.f, fmaf(px[j], x, fmaf(py[j], y, pz[j] * z)), s));
                }
            }
#pragma unroll
            for (int j = 0; j < 8; j++) {
#pragma unroll
                for (int o = 1; o < 64; o <<= 1) bd[j] = fminf(bd[j], __shfl_xor(bd[j], o));
            }
            if (lane == 0) {
#pragma unroll
                for (int j = 0; j < 8; j++) {
                    int pi = pbase + j;
                    if (pi < Pl) {
                        float p2 = fmaf(px[j], px[j], fmaf(py[j], py[j], pz[j] * pz[j]));
                        pgnmin[(size_t)((n - 1) * 3240 + loff + pi) * 4 + h] =
                            __float_as_uint(fmaxf(bd[j] + p2, 0.f));
                    }
                }
            }
        }
    }
    else if (b < 3408) {
        // ================= gp (float4 tile, deferred q^2) =================
        int t = b - 1648;
        int g = t / 160, tr = t % 160;
        int level, Pl, pstart; const float* P;
        if (g == 0)     { level = 0; Pl = 156;  P = pc0; pstart = 0; }
        else if (g < 3) { level = 1; Pl = 618;  P = pc1; pstart = (g - 1) * 320; }
        else            { level = 2; Pl = 2466; P = pc2; pstart = (g - 3) * 320; }
        int n = tr / 40, qc = tr % 40;
        int tp = Pl - pstart; if (tp > 320) tp = 320;
        const float* pn = P + ((size_t)n * Pl + pstart) * 3;
        for (int i = tid; i < tp; i += 256) {
            float x = pn[i * 3 + 0], y = pn[i * 3 + 1], z = pn[i * 3 + 2];
            s_tile[i] = make_float4(x, y, z, fmaf(x, x, fmaf(y, y, z * z)));
        }
        __syncthreads();
        int q = qc * 256 + tid; bool vq = (q < PGT);
        const float* g3 = gtp + (size_t)n * PGT * 3;
        float qx = 0.f, qy = 0.f, qz = 0.f;
        if (vq) { qx = g3[q * 3 + 0]; qy = g3[q * 3 + 1]; qz = g3[q * 3 + 2]; }
        float q2 = fmaf(qx, qx, fmaf(qy, qy, qz * qz));
        float bd = 3e38f;                     // tracks |p|^2 - 2 p.q  (q^2 added at end)
        int p = 0;
        for (; p + 4 <= tp; p += 4) {
            float4 a0 = s_tile[p], a1 = s_tile[p + 1], a2 = s_tile[p + 2], a3 = s_tile[p + 3];
            float d0 = fmaf(-2.f, fmaf(a0.x, qx, fmaf(a0.y, qy, a0.z * qz)), a0.w);
            float d1 = fmaf(-2.f, fmaf(a1.x, qx, fmaf(a1.y, qy, a1.z * qz)), a1.w);
            float d2 = fmaf(-2.f, fmaf(a2.x, qx, fmaf(a2.y, qy, a2.z * qz)), a2.w);
            float d3 = fmaf(-2.f, fmaf(a3.x, qx, fmaf(a3.y, qy, a3.z * qz)), a3.w);
            bd = fminf(bd, fminf(fminf(d0, d1), fminf(d2, d3)));
        }
        for (; p < tp; p++) {
            float4 a0 = s_tile[p];
            bd = fminf(bd, fmaf(-2.f, fmaf(a0.x, qx, fmaf(a0.y, qy, a0.z * qz)), a0.w));
        }
        if (vq) atomicMin(&gpmin[(level * 4 + n) * PGT + q], __float_as_uint(fmaxf(bd + q2, 0.f)));
    }
    else if (b < 3460) {
        // ================= laplace + move =================
        int t = b - 3408;
        int level, Pl, bstart; const float* P; const float* B; const int* L;
        if (t < 3)       { level = 0; Pl = 156;  P = pc0; B = pb0; L = lp0; bstart = 0; }
        else if (t < 13) { level = 1; Pl = 618;  P = pc1; B = pb1; L = lp1; bstart = 3; }
        else             { level = 2; Pl = 2466; P = pc2; B = pb2; L = lp2; bstart = 13; }
        int item = (t - bstart) * 256 + tid;
        float lap_s = 0.f, mov_s = 0.f;
        if (item < 4 * Pl) {
            int n = item / Pl, p = item % Pl;
            const int* lr = L + p * 10;
            float cntv = (float)lr[9];
            const float* Bn = B + (size_t)n * Pl * 3;
            const float* Pn = P + (size_t)n * Pl * 3;
            float sbx = 0, sby = 0, sbz = 0, spx = 0, spy = 0, spz = 0;
#pragma unroll
            for (int k = 0; k < 8; k++) {
                int id = lr[k];
                if (id >= 0) {
                    sbx += Bn[id * 3 + 0]; sby += Bn[id * 3 + 1]; sbz += Bn[id * 3 + 2];
                    spx += Pn[id * 3 + 0]; spy += Pn[id * 3 + 1]; spz += Pn[id * 3 + 2];
                }
            }
            float bx = Bn[p * 3], by = Bn[p * 3 + 1], bz = Bn[p * 3 + 2];
            float vx = Pn[p * 3], vy = Pn[p * 3 + 1], vz = Pn[p * 3 + 2];
            float dx = (bx - sbx / cntv) - (vx - spx / cntv);
            float dy = (by - sby / cntv) - (vy - spy / cntv);
            float dz = (bz - sbz / cntv) - (vz - spz / cntv);
            lap_s = dx * dx + dy * dy + dz * dz;
            float mx = bx - vx, my = by - vy, mz = bz - vz;
            mov_s = mx * mx + my * my + mz * mz;
        }
        float lsum = blockReduceF(lap_s, s_red);
        float msum = blockReduceF(mov_s, s_red);
        if (tid == 0) {
            const double lc[3] = {0.2, 1.0, 1.0};
            double inv = 1.0 / (4.0 * (double)Pl);
            part[2 * t]     = (double)lsum * (0.5 * lc[level] * inv);
            part[2 * t + 1] = (level > 0) ? (double)msum * (0.1 * lc[level] * inv) : 0.0;
        }
    }
    else {
        // ================= BCE =================
        int t = b - 3460;
        const float4* g4 = (const float4*)gimg;
        const float4* r4 = (const float4*)rec;
        const int N4 = 602112 / 4;
        float s = 0.f;
        for (int i = t * 256 + tid; i < N4; i += 64 * 256) {
            float4 gv = g4[i], rv = r4[i];
            s -= gv.x * __logf(rv.x) + (1.f - gv.x) * __logf(1.f - rv.x);
            s -= gv.y * __logf(rv.y) + (1.f - gv.y) * __logf(1.f - rv.y);
            s -= gv.z * __logf(rv.z) + (1.f - gv.z) * __logf(1.f - rv.z);
            s -= gv.w * __logf(rv.w) + (1.f - gv.w) * __logf(1.f - rv.w);
        }
        float sum = blockReduceF(s, s_red);
        if (tid == 0) part[104 + t] = (double)sum / 602112.0;
    }
}

// ---------------- K2: edge+normal, pg/gp reduce, finalize ----------------
__global__ __launch_bounds__(256) void k2_kernel(
    const float* __restrict__ pc0, const float* __restrict__ pc1, const float* __restrict__ pc2,
    const int* __restrict__ e0, const int* __restrict__ e1, const int* __restrict__ e2,
    const float* __restrict__ gtn,
    const unsigned long long* __restrict__ pg0min, const unsigned* __restrict__ pgnmin,
    const unsigned* __restrict__ gpmin,
    double* __restrict__ part, unsigned* __restrict__ done, float* __restrict__ out)
{
    __shared__ float s_red[4];
    __shared__ double s_redd[4];
    __shared__ int s_flag;
    const int b = blockIdx.x, tid = threadIdx.x;
    if (b < 153) {
        int level, El, Pl, loff, bstart; const float* P; const int* E;
        if (b < 8)       { level = 0; El = 462;  Pl = 156;  loff = 0;   bstart = 0;  P = pc0; E = e0; }
        else if (b < 37) { level = 1; El = 1848; Pl = 618;  loff = 156; bstart = 8;  P = pc1; E = e1; }
        else             { level = 2; El = 7392; Pl = 2466; loff = 774; bstart = 37; P = pc2; E = e2; }
        int item = (b - bstart) * 256 + tid;
        float es = 0.f, ns = 0.f;
        if (item < 4 * El) {
            int n = item / El, e = item % El;
            int a = E[e * 2 + 0], b2 = E[e * 2 + 1];
            const float* Pn = P + (size_t)n * Pl * 3;
            float ax = Pn[a * 3], ay = Pn[a * 3 + 1], az = Pn[a * 3 + 2];
            float bx = Pn[b2 * 3], by = Pn[b2 * 3 + 1], bz = Pn[b2 * 3 + 2];
            float ex = ax - bx, ey = ay - by, ez = az - bz;
            float el2 = ex * ex + ey * ey + ez * ez;
            es = el2;
            float einv = 1.f / fmaxf(sqrtf(el2), 1e-12f);
            const unsigned long long* kp = &pg0min[(size_t)(loff + a) * 4];
            unsigned long long k0 = kp[0] < kp[1] ? kp[0] : kp[1];
            unsigned long long k1 = kp[2] < kp[3] ? kp[2] : kp[3];
            unsigned long long k = k0 < k1 ? k0 : k1;   // min dist; min idx tie-break
            int ig = (int)(k & 0xFFFFFFFFull);
            const float* Nv = gtn + ((size_t)n * PGT + ig) * 3;
            float nx = Nv[0], ny = Nv[1], nz = Nv[2];
            float ninv = 1.f / fmaxf(sqrtf(nx * nx + ny * ny + nz * nz), 1e-12f);
            ns = fabsf((ex * nx + ey * ny + ez * nz) * einv * ninv);
        }
        float esum = blockReduceF(es, s_red);
        float nsum = blockReduceF(ns, s_red);
        if (tid == 0) {
            double inv = 1.0 / (4.0 * (double)El);
            part[168 + b] = (double)esum * (0.1 * inv);
            part[321 + b] = (double)nsum * (0.00016 * inv);
        }
    } else if (b < 165) {
        int i = b - 153, level = i >> 2, n = i & 3;
        int Pl = (level == 0) ? 156 : (level == 1) ? 618 : 2466;
        int loff = (level == 0) ? 0 : (level == 1) ? 156 : 774;
        double s = 0.0;
        if (n == 0) {
            const unsigned long long* base = &pg0min[(size_t)loff * 4];
            for (int p = tid; p < Pl; p += 256) {
                const unsigned long long* kp = &base[(size_t)p * 4];
                unsigned long long k0 = kp[0] < kp[1] ? kp[0] : kp[1];
                unsigned long long k1 = kp[2] < kp[3] ? kp[2] : kp[3];
                unsigned long long k = k0 < k1 ? k0 : k1;
                s += (double)__uint_as_float((unsigned)(k >> 32));
            }
        } else {
            const uint4* base = (const uint4*)&pgnmin[(size_t)((n - 1) * 3240 + loff) * 4];
            for (int p = tid; p < Pl; p += 256) {
                uint4 v = base[p];
                unsigned m = min(min(v.x, v.y), min(v.z, v.w));
                s += (double)__uint_as_float(m);
            }
        }
        s = blockReduceD(s, s_redd);
        if (tid == 0) part[474 + i] = s / (4.0 * (double)Pl);
    } else {
        int i = b - 165, level = i >> 2, n = i & 3;
        const unsigned* gm = gpmin + (size_t)(level * 4 + n) * PGT;
        double s = 0.0;
        for (int q = tid; q < PGT; q += 256) s += (double)__uint_as_float(gm[q]);
        s = blockReduceD(s, s_redd);
        if (tid == 0) part[486 + i] = s * (0.55 / (4.0 * (double)PGT));
    }
    // ----- last-done finalize (177 atomics on one line: proven fine in r3) -----
    __threadfence();
    if (tid == 0) {
        unsigned old = atomicAdd(done, 1u);
        s_flag = (old == CNT0 + 176u) ? 1 : 0;
        __threadfence();
    }
    __syncthreads();
    if (s_flag) {
        double s = 0.0;
        for (int i = tid; i < NSLOT; i += 256) s += part[i];
        s = blockReduceD(s, s_redd);
        if (tid == 0) out[0] = (float)s;
    }
}

extern "C" void kernel_launch(void* const* d_in, const int* in_sizes, int n_in,
                              void* d_out, int out_size, void* d_ws, size_t ws_size,
                              hipStream_t stream) {
    const float *pc[3], *pb[3]; const int *ed[3], *lp[3];
    bool dict = (n_in >= 2 && in_sizes[1] == in_sizes[0]);   // dict vs signature order
    if (dict) {
        for (int i = 0; i < 3; i++) {
            pc[i] = (const float*)d_in[4 * i + 0];
            pb[i] = (const float*)d_in[4 * i + 1];
            ed[i] = (const int*)  d_in[4 * i + 2];
            lp[i] = (const int*)  d_in[4 * i + 3];
        }
    } else {
        for (int i = 0; i < 3; i++) {
            pc[i] = (const float*)d_in[i];
            pb[i] = (const float*)d_in[3 + i];
            ed[i] = (const int*)  d_in[6 + i];
            lp[i] = (const int*)  d_in[9 + i];
        }
    }
    const float* gtp  = (const float*)d_in[12];
    const float* gtn  = (const float*)d_in[13];
    const float* gimg = (const float*)d_in[14];
    const float* rec  = (const float*)d_in[15];

    unsigned*           done   = (unsigned*)d_ws;
    unsigned*           gpmin  = (unsigned*)((char*)d_ws + 256);
    unsigned long long* pg0min = (unsigned long long*)((char*)d_ws + 480384);
    unsigned*           pgnmin = (unsigned*)((char*)d_ws + 584064);
    double*             part   = (double*)((char*)d_ws + 739584);

    // one memset: done -> CNT0, gpmin -> 3.39e38f bits
    hipMemsetAsync(d_ws, 0x7F, 480256, stream);

    k1_kernel<<<3524, 256, 0, stream>>>(pc[0], pc[1], pc[2], pb[0], pb[1], pb[2],
                                        lp[0], lp[1], lp[2], gtp, gimg, rec,
                                        gpmin, pg0min, pgnmin, part);
    k2_kernel<<<177, 256, 0, stream>>>(pc[0], pc[1], pc[2], ed[0], ed[1], ed[2],
                                       gtn, pg0min, pgnmin, gpmin, part, done, (float*)d_out);
}

// Round 6
// 157.364 us; speedup vs baseline: 2.5875x; 1.0154x over previous
//
#include <hip/hip_runtime.h>
#include <math.h>

#define PGT 10000
#define CNT0 0x7F7F7F7Fu

// ws layout (bytes):
//   0                  done counter (K2 only; memset 0x7F -> CNT0)
//   [256, 480256)      gpmin   u32[3*4*10000] float-bits  (memset 0x7F -> 3.39e38)
//   [480256, 506176)   pg0min  u64[3240]  ((distbits<<32)|idx), atomicMin merge (n==0)
//   [506176, 545056)   pgnmin  u32[3*3240] distbits, atomicMin merge (n=1..3)
//   [545280, +3984)    part    double[498], pre-scaled, plain stores
// part slots: lap/move [0,104) bce [104,168) edge [168,321) norm [321,474)
//             pgred [474,486) gpred [486,498)
#define NSLOT 498

static __device__ __forceinline__ float waveReduceSum(float v) {
#pragma unroll
    for (int o = 32; o; o >>= 1) v += __shfl_down(v, o);
    return v;
}
static __device__ __forceinline__ double waveReduceSumD(double v) {
#pragma unroll
    for (int o = 32; o; o >>= 1) v += __shfl_down(v, o);
    return v;
}
static __device__ __forceinline__ float blockReduceF(float v, float* red) {
    v = waveReduceSum(v);
    __syncthreads();
    if ((threadIdx.x & 63) == 0) red[threadIdx.x >> 6] = v;
    __syncthreads();
    return red[0] + red[1] + red[2] + red[3];
}
static __device__ __forceinline__ double blockReduceD(double v, double* red) {
    v = waveReduceSumD(v);
    __syncthreads();
    if ((threadIdx.x & 63) == 0) red[threadIdx.x >> 6] = v;
    __syncthreads();
    return red[0] + red[1] + red[2] + red[3];
}

// ---------------- K1 ----------------
//  [0,1680)     fused chamfer: one pass computes each distance ONCE, feeding
//               row-min (pred side, registers) AND col-min (gt side, LDS ds_min)
//               block = (level, n, pred-chunk of 96, q-chunk of ~834)
//               lvl0: 2x12, lvl1: 7x12, lvl2: 26x12 chunks, x4 batches
//  [1680,1732)  laplace+move (52)
//  [1732,1796)  BCE (64)
__global__ __launch_bounds__(256) void k1_kernel(
    const float* __restrict__ pc0, const float* __restrict__ pc1, const float* __restrict__ pc2,
    const float* __restrict__ pb0, const float* __restrict__ pb1, const float* __restrict__ pb2,
    const int* __restrict__ lp0, const int* __restrict__ lp1, const int* __restrict__ lp2,
    const float* __restrict__ gtp, const float* __restrict__ gimg, const float* __restrict__ rec,
    unsigned* __restrict__ gpmin, unsigned long long* __restrict__ pg0min,
    unsigned* __restrict__ pgnmin, double* __restrict__ part)
{
    __shared__ unsigned s_col[896];    // 14 iters x 64 lanes (>= 834 live entries)
    __shared__ float s_red[4];
    const int b = blockIdx.x;
    const int tid = threadIdx.x;

    if (b < 1680) {
        // ----- decode (level, n, pchunk, qchunk) -----
        int level, n, pchunk, qchunk, Pl, loff; const float* P;
        if (b < 96)       { level = 0; Pl = 156;  loff = 0;   P = pc0; int t = b;       n = t / 24;  int r = t % 24;  pchunk = r / 12; qchunk = r % 12; }
        else if (b < 432) { level = 1; Pl = 618;  loff = 156; P = pc1; int t = b - 96;  n = t / 84;  int r = t % 84;  pchunk = r / 12; qchunk = r % 12; }
        else              { level = 2; Pl = 2466; loff = 774; P = pc2; int t = b - 432; n = t / 312; int r = t % 312; pchunk = r / 12; qchunk = r % 12; }
        const int wave = tid >> 6, lane = tid & 63;
        const int qbeg = qchunk * 834;
        const int qend = (qbeg + 834 < PGT) ? qbeg + 834 : PGT;
        const int Qlen = qend - qbeg;
        const int niter = (Qlen + 63) >> 6;
        for (int i = tid; i < 896; i += 256) s_col[i] = CNT0;
        __syncthreads();
        const float* pn = P + (size_t)n * Pl * 3;
        const float* g3 = gtp + (size_t)n * PGT * 3;
        const int pcbase = pchunk * 96;
        int rem = Pl - pcbase;
        const int ngroups = (rem >= 96) ? 3 : ((rem + 31) >> 5);

        for (int g = 0; g < ngroups; g++) {
            const int pbase = pcbase + g * 32 + wave * 8;
            float px[8], py[8], pz[8], p2[8];
#pragma unroll
            for (int j = 0; j < 8; j++) {
                int pi = pbase + j; int ps = (pi < Pl) ? pi : 0;
                px[j] = pn[ps * 3 + 0]; py[j] = pn[ps * 3 + 1]; pz[j] = pn[ps * 3 + 2];
                p2[j] = (pi < Pl) ? fmaf(px[j], px[j], fmaf(py[j], py[j], pz[j] * pz[j])) : 3e38f;
            }
            float bd[8];
#pragma unroll
            for (int j = 0; j < 8; j++) bd[j] = 3e38f;

            if (n == 0) {
                int bi[8];
#pragma unroll
                for (int j = 0; j < 8; j++) bi[j] = 0;
                for (int it = 0; it < niter; it++) {
                    int q = qbeg + it * 64 + lane;
                    bool vq = (q < qend);
                    const float* ga = g3 + (vq ? q : qend - 1) * 3;
                    float x = ga[0], y = ga[1], z = ga[2];
                    float q2 = vq ? fmaf(x, x, fmaf(y, y, z * z)) : 3e38f;
                    float cm = 3e38f;
#pragma unroll
                    for (int j = 0; j < 8; j++) {
                        float c = p2[j] + q2;
                        float t = fmaf(px[j], x, fmaf(py[j], y, pz[j] * z));
                        float d = fmaf(-2.f, t, c);
                        if (d < bd[j]) { bd[j] = d; bi[j] = q; }
                        cm = fminf(cm, d);
                    }
                    atomicMin(&s_col[it * 64 + lane], __float_as_uint(fmaxf(cm, 0.f)));
                }
#pragma unroll
                for (int j = 0; j < 8; j++) {
#pragma unroll
                    for (int o = 1; o < 64; o <<= 1) {
                        float od = __shfl_xor(bd[j], o);
                        int   oi = __shfl_xor(bi[j], o);
                        if (od < bd[j] || (od == bd[j] && oi < bi[j])) { bd[j] = od; bi[j] = oi; }
                    }
                }
                if (lane == 0) {
#pragma unroll
                    for (int j = 0; j < 8; j++) {
                        int pi = pbase + j;
                        if (pi < Pl) {
                            unsigned db = __float_as_uint(fmaxf(bd[j], 0.f));
                            atomicMin(&pg0min[loff + pi],
                                      ((unsigned long long)db << 32) | (unsigned)bi[j]);
                        }
                    }
                }
            } else {
                for (int it = 0; it < niter; it++) {
                    int q = qbeg + it * 64 + lane;
                    bool vq = (q < qend);
                    const float* ga = g3 + (vq ? q : qend - 1) * 3;
                    float x = ga[0], y = ga[1], z = ga[2];
                    float q2 = vq ? fmaf(x, x, fmaf(y, y, z * z)) : 3e38f;
                    float cm = 3e38f;
#pragma unroll
                    for (int j = 0; j < 8; j++) {
                        float c = p2[j] + q2;
                        float t = fmaf(px[j], x, fmaf(py[j], y, pz[j] * z));
                        float d = fmaf(-2.f, t, c);
                        bd[j] = fminf(bd[j], d);
                        cm = fminf(cm, d);
                    }
                    atomicMin(&s_col[it * 64 + lane], __float_as_uint(fmaxf(cm, 0.f)));
                }
#pragma unroll
                for (int j = 0; j < 8; j++) {
#pragma unroll
                    for (int o = 1; o < 64; o <<= 1) bd[j] = fminf(bd[j], __shfl_xor(bd[j], o));
                }
                if (lane == 0) {
#pragma unroll
                    for (int j = 0; j < 8; j++) {
                        int pi = pbase + j;
                        if (pi < Pl)
                            atomicMin(&pgnmin[(n - 1) * 3240 + loff + pi],
                                      __float_as_uint(fmaxf(bd[j], 0.f)));
                    }
                }
            }
        }
        // ----- col-min writeback (one atomic per (q, pred-chunk)) -----
        __syncthreads();
        unsigned* gm = gpmin + (size_t)(level * 4 + n) * PGT;
        for (int ql = tid; ql < Qlen; ql += 256)
            atomicMin(&gm[qbeg + ql], s_col[ql]);
    }
    else if (b < 1732) {
        // ================= laplace + move =================
        int t = b - 1680;
        int level, Pl, bstart; const float* P; const float* B; const int* L;
        if (t < 3)       { level = 0; Pl = 156;  P = pc0; B = pb0; L = lp0; bstart = 0; }
        else if (t < 13) { level = 1; Pl = 618;  P = pc1; B = pb1; L = lp1; bstart = 3; }
        else             { level = 2; Pl = 2466; P = pc2; B = pb2; L = lp2; bstart = 13; }
        int item = (t - bstart) * 256 + tid;
        float lap_s = 0.f, mov_s = 0.f;
        if (item < 4 * Pl) {
            int n = item / Pl, p = item % Pl;
            const int* lr = L + p * 10;
            float cntv = (float)lr[9];
            const float* Bn = B + (size_t)n * Pl * 3;
            const float* Pn = P + (size_t)n * Pl * 3;
            float sbx = 0, sby = 0, sbz = 0, spx = 0, spy = 0, spz = 0;
#pragma unroll
            for (int k = 0; k < 8; k++) {
                int id = lr[k];
                if (id >= 0) {
                    sbx += Bn[id * 3 + 0]; sby += Bn[id * 3 + 1]; sbz += Bn[id * 3 + 2];
                    spx += Pn[id * 3 + 0]; spy += Pn[id * 3 + 1]; spz += Pn[id * 3 + 2];
                }
            }
            float bx = Bn[p * 3], by = Bn[p * 3 + 1], bz = Bn[p * 3 + 2];
            float vx = Pn[p * 3], vy = Pn[p * 3 + 1], vz = Pn[p * 3 + 2];
            float dx = (bx - sbx / cntv) - (vx - spx / cntv);
            float dy = (by - sby / cntv) - (vy - spy / cntv);
            float dz = (bz - sbz / cntv) - (vz - spz / cntv);
            lap_s = dx * dx + dy * dy + dz * dz;
            float mx = bx - vx, my = by - vy, mz = bz - vz;
            mov_s = mx * mx + my * my + mz * mz;
        }
        float lsum = blockReduceF(lap_s, s_red);
        float msum = blockReduceF(mov_s, s_red);
        if (tid == 0) {
            const double lc[3] = {0.2, 1.0, 1.0};
            double inv = 1.0 / (4.0 * (double)Pl);
            part[2 * t]     = (double)lsum * (0.5 * lc[level] * inv);
            part[2 * t + 1] = (level > 0) ? (double)msum * (0.1 * lc[level] * inv) : 0.0;
        }
    }
    else {
        // ================= BCE =================
        int t = b - 1732;
        const float4* g4 = (const float4*)gimg;
        const float4* r4 = (const float4*)rec;
        const int N4 = 602112 / 4;
        float s = 0.f;
        for (int i = t * 256 + tid; i < N4; i += 64 * 256) {
            float4 gv = g4[i], rv = r4[i];
            s -= gv.x * __logf(rv.x) + (1.f - gv.x) * __logf(1.f - rv.x);
            s -= gv.y * __logf(rv.y) + (1.f - gv.y) * __logf(1.f - rv.y);
            s -= gv.z * __logf(rv.z) + (1.f - gv.z) * __logf(1.f - rv.z);
            s -= gv.w * __logf(rv.w) + (1.f - gv.w) * __logf(1.f - rv.w);
        }
        float sum = blockReduceF(s, s_red);
        if (tid == 0) part[104 + t] = (double)sum / 602112.0;
    }
}

// ---------------- K2: edge+normal, pg/gp reduce, finalize ----------------
__global__ __launch_bounds__(256) void k2_kernel(
    const float* __restrict__ pc0, const float* __restrict__ pc1, const float* __restrict__ pc2,
    const int* __restrict__ e0, const int* __restrict__ e1, const int* __restrict__ e2,
    const float* __restrict__ gtn,
    const unsigned long long* __restrict__ pg0min, const unsigned* __restrict__ pgnmin,
    const unsigned* __restrict__ gpmin,
    double* __restrict__ part, unsigned* __restrict__ done, float* __restrict__ out)
{
    __shared__ float s_red[4];
    __shared__ double s_redd[4];
    __shared__ int s_flag;
    const int b = blockIdx.x, tid = threadIdx.x;
    if (b < 153) {
        int level, El, Pl, loff, bstart; const float* P; const int* E;
        if (b < 8)       { level = 0; El = 462;  Pl = 156;  loff = 0;   bstart = 0;  P = pc0; E = e0; }
        else if (b < 37) { level = 1; El = 1848; Pl = 618;  loff = 156; bstart = 8;  P = pc1; E = e1; }
        else             { level = 2; El = 7392; Pl = 2466; loff = 774; bstart = 37; P = pc2; E = e2; }
        int item = (b - bstart) * 256 + tid;
        float es = 0.f, ns = 0.f;
        if (item < 4 * El) {
            int n = item / El, e = item % El;
            int a = E[e * 2 + 0], b2 = E[e * 2 + 1];
            const float* Pn = P + (size_t)n * Pl * 3;
            float ax = Pn[a * 3], ay = Pn[a * 3 + 1], az = Pn[a * 3 + 2];
            float bx = Pn[b2 * 3], by = Pn[b2 * 3 + 1], bz = Pn[b2 * 3 + 2];
            float ex = ax - bx, ey = ay - by, ez = az - bz;
            float el2 = ex * ex + ey * ey + ez * ez;
            es = el2;
            float einv = 1.f / fmaxf(sqrtf(el2), 1e-12f);
            unsigned long long k = pg0min[loff + a];
            int ig = (int)(k & 0xFFFFFFFFull);
            const float* Nv = gtn + ((size_t)n * PGT + ig) * 3;
            float nx = Nv[0], ny = Nv[1], nz = Nv[2];
            float ninv = 1.f / fmaxf(sqrtf(nx * nx + ny * ny + nz * nz), 1e-12f);
            ns = fabsf((ex * nx + ey * ny + ez * nz) * einv * ninv);
        }
        float esum = blockReduceF(es, s_red);
        float nsum = blockReduceF(ns, s_red);
        if (tid == 0) {
            double inv = 1.0 / (4.0 * (double)El);
            part[168 + b] = (double)esum * (0.1 * inv);
            part[321 + b] = (double)nsum * (0.00016 * inv);
        }
    } else if (b < 165) {
        int i = b - 153, level = i >> 2, n = i & 3;
        int Pl = (level == 0) ? 156 : (level == 1) ? 618 : 2466;
        int loff = (level == 0) ? 0 : (level == 1) ? 156 : 774;
        double s = 0.0;
        if (n == 0) {
            for (int p = tid; p < Pl; p += 256)
                s += (double)__uint_as_float((unsigned)(pg0min[loff + p] >> 32));
        } else {
            const unsigned* base = &pgnmin[(n - 1) * 3240 + loff];
            for (int p = tid; p < Pl; p += 256)
                s += (double)__uint_as_float(base[p]);
        }
        s = blockReduceD(s, s_redd);
        if (tid == 0) part[474 + i] = s / (4.0 * (double)Pl);
    } else {
        int i = b - 165, level = i >> 2, n = i & 3;
        const unsigned* gm = gpmin + (size_t)(level * 4 + n) * PGT;
        double s = 0.0;
        for (int q = tid; q < PGT; q += 256) s += (double)__uint_as_float(gm[q]);
        s = blockReduceD(s, s_redd);
        if (tid == 0) part[486 + i] = s * (0.55 / (4.0 * (double)PGT));
    }
    // ----- last-done finalize (177 atomics on one line: proven fine) -----
    __threadfence();
    if (tid == 0) {
        unsigned old = atomicAdd(done, 1u);
        s_flag = (old == CNT0 + 176u) ? 1 : 0;
        __threadfence();
    }
    __syncthreads();
    if (s_flag) {
        double s = 0.0;
        for (int i = tid; i < NSLOT; i += 256) s += part[i];
        s = blockReduceD(s, s_redd);
        if (tid == 0) out[0] = (float)s;
    }
}

extern "C" void kernel_launch(void* const* d_in, const int* in_sizes, int n_in,
                              void* d_out, int out_size, void* d_ws, size_t ws_size,
                              hipStream_t stream) {
    const float *pc[3], *pb[3]; const int *ed[3], *lp[3];
    bool dict = (n_in >= 2 && in_sizes[1] == in_sizes[0]);   // dict vs signature order
    if (dict) {
        for (int i = 0; i < 3; i++) {
            pc[i] = (const float*)d_in[4 * i + 0];
            pb[i] = (const float*)d_in[4 * i + 1];
            ed[i] = (const int*)  d_in[4 * i + 2];
            lp[i] = (const int*)  d_in[4 * i + 3];
        }
    } else {
        for (int i = 0; i < 3; i++) {
            pc[i] = (const float*)d_in[i];
            pb[i] = (const float*)d_in[3 + i];
            ed[i] = (const int*)  d_in[6 + i];
            lp[i] = (const int*)  d_in[9 + i];
        }
    }
    const float* gtp  = (const float*)d_in[12];
    const float* gtn  = (const float*)d_in[13];
    const float* gimg = (const float*)d_in[14];
    const float* rec  = (const float*)d_in[15];

    unsigned*           done   = (unsigned*)d_ws;
    unsigned*           gpmin  = (unsigned*)((char*)d_ws + 256);
    unsigned long long* pg0min = (unsigned long long*)((char*)d_ws + 480256);
    unsigned*           pgnmin = (unsigned*)((char*)d_ws + 506176);
    double*             part   = (double*)((char*)d_ws + 545280);

    // one memset: done -> CNT0, gpmin/pg0min/pgnmin -> +huge bits
    hipMemsetAsync(d_ws, 0x7F, 545056, stream);

    k1_kernel<<<1796, 256, 0, stream>>>(pc[0], pc[1], pc[2], pb[0], pb[1], pb[2],
                                        lp[0], lp[1], lp[2], gtp, gimg, rec,
                                        gpmin, pg0min, pgnmin, part);
    k2_kernel<<<177, 256, 0, stream>>>(pc[0], pc[1], pc[2], ed[0], ed[1], ed[2],
                                       gtn, pg0min, pgnmin, gpmin, part, done, (float*)d_out);
}